// Round 5
// baseline (41.118 us; speedup 1.0000x reference)
//
#include <hip/hip_runtime.h>

// BPS tokenizer: per (batch, basis) argmin_n |pc[b,n]-basis[p]|^2 -> [dist,dx,dy,dz].
// B=16, N=4096, P=4096.
//
// R5: cloud moved OFF the LDS pipe into SGPRs. Prologue kernel writes a scaled
// pair array to ws: pair j of batch b = {-2x0,-2x1,-2y0,-2y1,-2z0,-2z1,w0,w1},
// w=|p|^2. Main kernel: 256 blocks (b x ptile) x 1024 threads; wave g scans
// pairs [g*128, g*128+128) via s_load_dwordx16 (scalar pipe — zero DS/VMEM in
// the hot loop). Point pairs feed v_pk_fma_f32 as the single SGPR operand;
// basis (Q=4 per thread) lives in VGPRs. key = fma(-2x,bx,fma(-2y,by,
// fma(-2z,bz,w))) = d2-|b|^2 (same argmin). v_min3 chunk-min over 8-pt chunks,
// (val, chunkId) lexicographic reduce, winning chunk rescanned from ws with the
// identical fma chain -> exact first-index tie-break.

typedef __attribute__((ext_vector_type(2)))  float f32x2;
typedef __attribute__((ext_vector_type(16))) float f32x16;

#define NB 16
#define NN 4096
#define NP 4096
#define PT 256
#define NW 16
#define THREADS 1024
#define NCHUNK 32          // chunks per wave; chunk = 4 pairs = 8 points

__device__ __forceinline__ float min3f(float a, float b, float c) {
    float r;
    asm("v_min3_f32 %0, %1, %2, %3" : "=v"(r) : "v"(a), "v"(b), "v"(c));
    return r;
}
// v_pk_fma_f32 with the point data (SGPR pair) as src0 — 1 scalar read/instr.
__device__ __forceinline__ f32x2 pk_fma_svv(f32x2 a_s, f32x2 b_v, f32x2 c_v) {
    f32x2 d;
    asm("v_pk_fma_f32 %0, %1, %2, %3" : "=v"(d) : "s"(a_s), "v"(b_v), "v"(c_v));
    return d;
}

// ---------- prologue: build scaled pair array in ws ----------
__global__ __launch_bounds__(256) void bps_prep(const float* __restrict__ pc,
                                                float* __restrict__ wsf) {
#pragma clang fp contract(off)
    const int tid = blockIdx.x * 256 + threadIdx.x;   // one thread per 4 points
    const int b   = tid >> 10;
    const int qd  = tid & 1023;
    const float4* pc4 = (const float4*)(pc + (size_t)b * NN * 3);
    const float4 f0 = pc4[3*qd+0], f1 = pc4[3*qd+1], f2 = pc4[3*qd+2];
    const float X[4] = {f0.x, f0.w, f1.z, f2.y};
    const float Y[4] = {f0.y, f1.x, f1.w, f2.z};
    const float Z[4] = {f0.z, f1.y, f2.x, f2.w};
    float W[4];
    #pragma unroll
    for (int j = 0; j < 4; ++j) W[j] = (X[j]*X[j] + Y[j]*Y[j]) + Z[j]*Z[j];
    float4* dst = (float4*)(wsf + ((((size_t)b << 11) + 2*qd) << 3));
    dst[0] = make_float4(-2.f*X[0], -2.f*X[1], -2.f*Y[0], -2.f*Y[1]);
    dst[1] = make_float4(-2.f*Z[0], -2.f*Z[1], W[0], W[1]);
    dst[2] = make_float4(-2.f*X[2], -2.f*X[3], -2.f*Y[2], -2.f*Y[3]);
    dst[3] = make_float4(-2.f*Z[2], -2.f*Z[3], W[2], W[3]);
}

// ---------- main ----------
__global__ __launch_bounds__(THREADS, 4) void bps_kernel(
    const float* __restrict__ wsf,    // scaled pair array [B][2048][8]
    const float* __restrict__ basis,  // [P, 3]
    float* __restrict__ out)          // [B, P, 4]
{
#pragma clang fp contract(off)
    __shared__ float redv[NW][4][64];   // 16 KB
    __shared__ int   redi[NW][4][64];   // 16 KB

    const int b     = blockIdx.x >> 4;
    const int ptile = blockIdx.x & 15;
    const int t     = threadIdx.x;
    const int l     = t & 63;
    const int g     = t >> 6;           // wave id 0..15

    // wave-uniform scalar base for this wave's 128-pair slice
    const int gs = __builtin_amdgcn_readfirstlane(g);
    const float* sbase = wsf + ((((size_t)b << 11) + (gs << 7)) << 3);

    // ---- packed basis registers: Q=4, p = ptile*256 + 64q + l ----
    const int pbase = (ptile << 8) + l;
#define DECLQ(Q) \
    const float bxs##Q = basis[3*(pbase + 64*Q) + 0]; \
    const float bys##Q = basis[3*(pbase + 64*Q) + 1]; \
    const float bzs##Q = basis[3*(pbase + 64*Q) + 2]; \
    const f32x2 bxx##Q = {bxs##Q, bxs##Q}; \
    const f32x2 byy##Q = {bys##Q, bys##Q}; \
    const f32x2 bzz##Q = {bzs##Q, bzs##Q};
    DECLQ(0) DECLQ(1) DECLQ(2) DECLQ(3)
#undef DECLQ

    float gm0 = __builtin_inff(), gm1 = gm0, gm2 = gm0, gm3 = gm0;
    int   cb0 = 0, cb1 = 0, cb2 = 0, cb3 = 0;

    for (int c = 0; c < NCHUNK; ++c) {
        f32x16 L, H;
        const int off0 = c * 128;       // 4 pairs * 32 B
        asm volatile("s_load_dwordx16 %0, %2, %3\n\t"
                     "s_load_dwordx16 %1, %2, %4\n\t"
                     "s_waitcnt lgkmcnt(0)"
                     : "=&s"(L), "=&s"(H)
                     : "s"(sbase), "s"(off0), "s"(off0 + 64));
        float cm0, cm1, cm2, cm3;
#define PAIR(VEC, BASE, FIRST) { \
        const f32x2 xs = __builtin_shufflevector(VEC, VEC, BASE+0, BASE+1); \
        const f32x2 ys = __builtin_shufflevector(VEC, VEC, BASE+2, BASE+3); \
        const f32x2 zs = __builtin_shufflevector(VEC, VEC, BASE+4, BASE+5); \
        f32x2 wv = __builtin_shufflevector(VEC, VEC, BASE+6, BASE+7); \
        asm("" : "+v"(wv));  /* pin w-pair to VGPRs once, shared across Q */ \
        _Pragma("unroll") \
        for (int dummy = 0; dummy < 1; ++dummy) { \
            const f32x2 k0 = pk_fma_svv(xs, bxx0, pk_fma_svv(ys, byy0, pk_fma_svv(zs, bzz0, wv))); \
            const f32x2 k1 = pk_fma_svv(xs, bxx1, pk_fma_svv(ys, byy1, pk_fma_svv(zs, bzz1, wv))); \
            const f32x2 k2 = pk_fma_svv(xs, bxx2, pk_fma_svv(ys, byy2, pk_fma_svv(zs, bzz2, wv))); \
            const f32x2 k3 = pk_fma_svv(xs, bxx3, pk_fma_svv(ys, byy3, pk_fma_svv(zs, bzz3, wv))); \
            if (FIRST) { cm0 = fminf(k0.x, k0.y); cm1 = fminf(k1.x, k1.y); \
                         cm2 = fminf(k2.x, k2.y); cm3 = fminf(k3.x, k3.y); } \
            else { cm0 = min3f(cm0, k0.x, k0.y); cm1 = min3f(cm1, k1.x, k1.y); \
                   cm2 = min3f(cm2, k2.x, k2.y); cm3 = min3f(cm3, k3.x, k3.y); } \
        } }
        PAIR(L, 0, 1)
        PAIR(L, 8, 0)
        PAIR(H, 0, 0)
        PAIR(H, 8, 0)
#undef PAIR
        const int C = (g << 5) + c;     // global chunk id 0..511, ascending n
        if (cm0 < gm0) { gm0 = cm0; cb0 = C; }
        if (cm1 < gm1) { gm1 = cm1; cb1 = C; }
        if (cm2 < gm2) { gm2 = cm2; cb2 = C; }
        if (cm3 < gm3) { gm3 = cm3; cb3 = C; }
    }

    redv[g][0][l] = gm0; redi[g][0][l] = cb0;
    redv[g][1][l] = gm1; redi[g][1][l] = cb1;
    redv[g][2][l] = gm2; redi[g][2][l] = cb2;
    redv[g][3][l] = gm3; redi[g][3][l] = cb3;

    __syncthreads();

    // ---- reduce 16 waves lexicographically, rescan winning chunk from ws ----
    if (t < PT) {
        const int q   = t >> 6;
        const int pl2 = t & 63;
        float bm = redv[0][q][pl2];
        int   bC = redi[0][q][pl2];
        #pragma unroll
        for (int gg = 1; gg < NW; ++gg) {
            const float v = redv[gg][q][pl2];
            const int   i = redi[gg][q][pl2];
            if (v < bm || (v == bm && i < bC)) { bm = v; bC = i; }
        }
        const int p  = (ptile << 8) + (q << 6) + pl2;
        const float bx = basis[3*p+0], by = basis[3*p+1], bz = basis[3*p+2];

        const float4* wp = (const float4*)(wsf + ((((size_t)b << 11) + (bC << 2)) << 3));
        int found = 0;
        float nx = 0.f, ny = 0.f, nz = 0.f;
        #pragma unroll
        for (int j = 0; j < 4; ++j) {            // pairs in ascending n
            const float4 A = wp[2*j];            // {-2x0,-2x1,-2y0,-2y1}
            const float4 Bv = wp[2*j+1];         // {-2z0,-2z1,w0,w1}
            const float k0 = fmaf(A.x, bx, fmaf(A.z, by, fmaf(Bv.x, bz, Bv.z)));
            const float k1 = fmaf(A.y, bx, fmaf(A.w, by, fmaf(Bv.y, bz, Bv.w)));
            if (!found && k0 == bm) { found = 1; nx = -0.5f*A.x; ny = -0.5f*A.z; nz = -0.5f*Bv.x; }
            if (!found && k1 == bm) { found = 1; nx = -0.5f*A.y; ny = -0.5f*A.w; nz = -0.5f*Bv.y; }
        }
        const float dx = nx - bx, dy = ny - by, dz = nz - bz;
        const float dist = sqrtf((dx*dx + dy*dy) + dz*dz);
        ((float4*)out)[(size_t)b * NP + p] = make_float4(dist, dx, dy, dz);
    }
}

extern "C" void kernel_launch(void* const* d_in, const int* in_sizes, int n_in,
                              void* d_out, int out_size, void* d_ws, size_t ws_size,
                              hipStream_t stream) {
    const float* pc    = (const float*)d_in[0];  // [16, 4096, 3]
    const float* basis = (const float*)d_in[1];  // [4096, 3]
    float* out = (float*)d_out;                  // [16, 4096, 4]
    float* wsf = (float*)d_ws;                   // 1 MB scaled pair array

    bps_prep<<<dim3(64), dim3(256), 0, stream>>>(pc, wsf);
    bps_kernel<<<dim3(NB * (NP / PT)), dim3(THREADS), 0, stream>>>(wsf, basis, out);
}

// Round 6
// 33.885 us; speedup vs baseline: 1.2134x; 1.2134x over previous
//
#include <hip/hip_runtime.h>

// BPS tokenizer: per (batch, basis) argmin_n |pc[b,n]-basis[p]|^2 -> [dist,dx,dy,dz].
// B=16, N=4096, P=4096.
//
// R6: back to broadcast-LDS (R3) but Q=16 basis/thread with single-copy uniform
// reads, N split 4-ways across blocks + tiny merge kernel.
//   main: 256 blocks (16 b x 4 ptile x 4 nsplit) x 512 threads (8 waves).
//   Block stages its 1024-pt slice in LDS as pairs {-2x0,-2x1,-2y0,-2y1}{-2z0,-2z1,w0,w1}.
//   Wave w scans 64 pairs; each ds_read_b128 is wave-uniform (broadcast) and
//   feeds 16 basis x 2 pts -> DS instrs/CU = 1024 (vs 4096 in R3).
//   key = fma(-2x,bx,fma(-2y,by,fma(-2z,bz,w))) = d2-|b|^2 (same argmin).
//   v_min3 chunk-min over 16-pt chunks, (val, chunkId) lexicographic:
//   in-block over 8 waves -> ws partial per (b,p,split); merge kernel combines
//   4 splits, rescans the winning 16-pt chunk from pc with the identical fmaf
//   chain (bit-exact) -> first-index tie-break, computes [dist,dx,dy,dz].

typedef __attribute__((ext_vector_type(2))) float f32x2;

#define NB 16
#define NN 4096
#define NP 4096
#define PT 1024            // basis per block
#define NSPLIT 4
#define NPTS (NN / NSPLIT) // 1024 points per block
#define NW 8               // waves per block
#define THREADS 512
#define NQ 16              // basis per thread
#define NCH 8              // chunks per wave (16 pts each)

__device__ __forceinline__ float min3f(float a, float b, float c) {
    float r;
    asm("v_min3_f32 %0, %1, %2, %3" : "=v"(r) : "v"(a), "v"(b), "v"(c));
    return r;
}
__device__ __forceinline__ f32x2 pk_fma(f32x2 a, f32x2 b, f32x2 c) {
    f32x2 d;
    asm("v_pk_fma_f32 %0, %1, %2, %3" : "=v"(d) : "v"(a), "v"(b), "v"(c));
    return d;
}

// ---------------- main: per-split partial argmin ----------------
__global__ __launch_bounds__(THREADS, 2) void bps_main(
    const float* __restrict__ pc,     // [B, N, 3]
    const float* __restrict__ basis,  // [P, 3]
    float* __restrict__ val_ws,       // [NSPLIT][B][4096]
    int*   __restrict__ idx_ws)       // [NSPLIT][B][4096]
{
#pragma clang fp contract(off)
    __shared__ float4 cloudP[NPTS * 2];      // 16 KB: 512 pairs x 32 B
    __shared__ float  redv[NW][NQ][64];      // 32 KB
    __shared__ int    redi[NW][NQ][64];      // 32 KB

    const int b  = blockIdx.x >> 4;
    const int pt = (blockIdx.x >> 2) & 3;
    const int sp = blockIdx.x & 3;
    const int t  = threadIdx.x;
    const int l  = t & 63;
    const int w  = t >> 6;                   // wave 0..7

    // ---- stage this block's 1024-pt slice (threads 0..255, 4 pts each) ----
    if (t < 256) {
        const float4* pc4 = (const float4*)(pc + (size_t)b * NN * 3 + (size_t)sp * NPTS * 3);
        const float4 f0 = pc4[3*t+0], f1 = pc4[3*t+1], f2 = pc4[3*t+2];
        const float X[4] = {f0.x, f0.w, f1.z, f2.y};
        const float Y[4] = {f0.y, f1.x, f1.w, f2.z};
        const float Z[4] = {f0.z, f1.y, f2.x, f2.w};
        float W[4];
        #pragma unroll
        for (int j = 0; j < 4; ++j) W[j] = (X[j]*X[j] + Y[j]*Y[j]) + Z[j]*Z[j];
        cloudP[4*t+0] = make_float4(-2.f*X[0], -2.f*X[1], -2.f*Y[0], -2.f*Y[1]);
        cloudP[4*t+1] = make_float4(-2.f*Z[0], -2.f*Z[1], W[0], W[1]);
        cloudP[4*t+2] = make_float4(-2.f*X[2], -2.f*X[3], -2.f*Y[2], -2.f*Y[3]);
        cloudP[4*t+3] = make_float4(-2.f*Z[2], -2.f*Z[3], W[2], W[3]);
    }

    // ---- 16 basis points per thread: p = pt*1024 + 64q + l ----
    f32x2 bxx[NQ], byy[NQ], bzz[NQ];
    {
        const int pb = (pt << 10) + l;
        #pragma unroll
        for (int q = 0; q < NQ; ++q) {
            const float bx = basis[3*(pb + 64*q) + 0];
            const float by = basis[3*(pb + 64*q) + 1];
            const float bz = basis[3*(pb + 64*q) + 2];
            bxx[q] = (f32x2){bx, bx};
            byy[q] = (f32x2){by, by};
            bzz[q] = (f32x2){bz, bz};
        }
    }

    __syncthreads();

    float gm[NQ];
    int   cb[NQ];
    #pragma unroll
    for (int q = 0; q < NQ; ++q) { gm[q] = __builtin_inff(); cb[q] = 0; }

    const int Cbase = (sp << 6) + (w << 3);   // global 16-pt chunk id base

    for (int c = 0; c < NCH; ++c) {
        const float4* chunk = cloudP + (((w << 6) + (c << 3)) << 1);  // 16 float4
        float cm[NQ];
        #pragma unroll
        for (int s = 0; s < 8; ++s) {
            const float4 A1 = chunk[2*s];     // wave-uniform -> broadcast
            const float4 A2 = chunk[2*s+1];
            const f32x2 xs = {A1.x, A1.y};
            const f32x2 ys = {A1.z, A1.w};
            const f32x2 zs = {A2.x, A2.y};
            const f32x2 wv = {A2.z, A2.w};
            #pragma unroll
            for (int q = 0; q < NQ; ++q) {
                const f32x2 k = pk_fma(xs, bxx[q], pk_fma(ys, byy[q], pk_fma(zs, bzz[q], wv)));
                if (s == 0) cm[q] = fminf(k.x, k.y);
                else        cm[q] = min3f(cm[q], k.x, k.y);
            }
        }
        #pragma unroll
        for (int q = 0; q < NQ; ++q)
            if (cm[q] < gm[q]) { gm[q] = cm[q]; cb[q] = Cbase + c; }  // ascending c
    }

    #pragma unroll
    for (int q = 0; q < NQ; ++q) { redv[w][q][l] = gm[q]; redi[w][q][l] = cb[q]; }

    __syncthreads();

    // ---- merge 8 waves lexicographically, write per-split partial to ws ----
    for (int s0 = t; s0 < PT; s0 += THREADS) {
        const int q  = s0 >> 6;
        const int l2 = s0 & 63;
        float bm = redv[0][q][l2];
        int   bC = redi[0][q][l2];
        #pragma unroll
        for (int w2 = 1; w2 < NW; ++w2) {
            const float v = redv[w2][q][l2];
            const int   i = redi[w2][q][l2];
            if (v < bm || (v == bm && i < bC)) { bm = v; bC = i; }
        }
        const int p = (pt << 10) + s0;
        val_ws[((size_t)sp << 16) + ((size_t)b << 12) + p] = bm;
        idx_ws[((size_t)sp << 16) + ((size_t)b << 12) + p] = bC;
    }
}

// ---------------- merge: combine splits, rescan winning chunk, emit ----------------
__global__ __launch_bounds__(256) void bps_merge(
    const float* __restrict__ pc,     // [B, N, 3]
    const float* __restrict__ basis,  // [P, 3]
    const float* __restrict__ val_ws,
    const int*   __restrict__ idx_ws,
    float* __restrict__ out)          // [B, P, 4]
{
#pragma clang fp contract(off)
    const int gid = blockIdx.x * 256 + threadIdx.x;   // 0..65535
    const int b   = gid >> 12;
    const int p   = gid & 4095;

    float bm = val_ws[((size_t)b << 12) + p];
    int   bC = idx_ws[((size_t)b << 12) + p];
    #pragma unroll
    for (int s = 1; s < NSPLIT; ++s) {
        const float v = val_ws[((size_t)s << 16) + ((size_t)b << 12) + p];
        const int   i = idx_ws[((size_t)s << 16) + ((size_t)b << 12) + p];
        if (v < bm || (v == bm && i < bC)) { bm = v; bC = i; }
    }

    const float bx = basis[3*p+0], by = basis[3*p+1], bz = basis[3*p+2];

    // rescan 16-pt chunk bC from pc with the IDENTICAL fma chain
    const float4* pp = (const float4*)(pc + (size_t)b * NN * 3) + 12 * bC;
    float4 F[12];
    #pragma unroll
    for (int j = 0; j < 12; ++j) F[j] = pp[j];
    const float* Ff = (const float*)F;

    int found = 0;
    float nx = 0.f, ny = 0.f, nz = 0.f;
    #pragma unroll
    for (int j = 0; j < 16; ++j) {           // ascending n -> first-index tie-break
        const float x = Ff[3*j+0];
        const float y = Ff[3*j+1];
        const float z = Ff[3*j+2];
        const float wq  = (x*x + y*y) + z*z;                 // == staging W
        const float key = fmaf(-2.f*x, bx, fmaf(-2.f*y, by, fmaf(-2.f*z, bz, wq)));
        if (!found && key == bm) { found = 1; nx = x; ny = y; nz = z; }
    }

    const float dx = nx - bx, dy = ny - by, dz = nz - bz;
    const float dist = sqrtf((dx*dx + dy*dy) + dz*dz);
    ((float4*)out)[((size_t)b << 12) + p] = make_float4(dist, dx, dy, dz);
}

extern "C" void kernel_launch(void* const* d_in, const int* in_sizes, int n_in,
                              void* d_out, int out_size, void* d_ws, size_t ws_size,
                              hipStream_t stream) {
    const float* pc    = (const float*)d_in[0];  // [16, 4096, 3]
    const float* basis = (const float*)d_in[1];  // [4096, 3]
    float* out = (float*)d_out;                  // [16, 4096, 4]

    float* val_ws = (float*)d_ws;                        // 1 MB
    int*   idx_ws = (int*)d_ws + (NSPLIT << 16);         // 1 MB

    bps_main<<<dim3(NB * 4 * NSPLIT), dim3(THREADS), 0, stream>>>(pc, basis, val_ws, idx_ws);
    bps_merge<<<dim3(NB * NP / 256), dim3(256), 0, stream>>>(pc, basis, val_ws, idx_ws, out);
}

// Round 7
// 32.201 us; speedup vs baseline: 1.2769x; 1.0523x over previous
//
#include <hip/hip_runtime.h>

// BPS tokenizer: per (batch, basis) argmin_n |pc[b,n]-basis[p]|^2 -> [dist,dx,dy,dz].
// B=16, N=4096, P=4096.
//
// R7: SCALAR v_fma (2 cyc) replaces v_pk_fma_f32 (measured-model ~8 cyc: packed
// fp32 has no FLOP-rate advantage on gfx950 -- all packed variants plateaued
// at ~22 us VALU). Per interaction: 3 fma + 0.5 min3 = 0.109 SIMD-cyc -> ~13 us.
//   grid: 256 blocks = 16 b x 4 ptile x 4 nsplit; 1024 thr = 16 waves (4/SIMD).
//   Block stages its 1024-pt slice in LDS as AoS float4 (x,y,z,w), w=|p|^2.
//   Wave w scans 64 pts; ds_read_b128 wave-uniform broadcast, feeds 16 basis.
//   key = fma(x,-2bx, fma(y,-2by, fma(z,-2bz, w))) = d2-|b|^2 (same argmin;
//   -2 folded into basis regs, exact pow2 scale).
//   v_min3 chunk-min over 16-pt chunks (value only), (val, chunkId) lexicographic
//   reduce in-block -> per-split partial in ws; merge kernel combines 4 splits,
//   rescans winning 16-pt chunk from pc with the IDENTICAL fma chain (bit-exact)
//   -> first-index tie-break, emits [dist,dx,dy,dz].

#define NB 16
#define NN 4096
#define NP 4096
#define NSPLIT 4
#define NPTS 1024          // points per block
#define NW 16              // waves per block
#define THREADS 1024
#define NQ 16              // basis per thread (wave covers 1024 basis)
#define NCH 4              // chunks per wave, 16 pts each

__device__ __forceinline__ float min3f(float a, float b, float c) {
    float r;
    asm("v_min3_f32 %0, %1, %2, %3" : "=v"(r) : "v"(a), "v"(b), "v"(c));
    return r;
}

// ---------------- main: per-split partial argmin ----------------
__global__ __launch_bounds__(THREADS, 4) void bps_main(
    const float* __restrict__ pc,     // [B, N, 3]
    const float* __restrict__ basis,  // [P, 3]
    float* __restrict__ val_ws,       // [NSPLIT][B][4096]
    int*   __restrict__ idx_ws)       // [NSPLIT][B][4096]
{
#pragma clang fp contract(off)
    __shared__ float4 cloud[NPTS];        // 16 KB, AoS (x,y,z,w)
    __shared__ float2 red[NW][NQ][64];    // 128 KB: (val, idx-bits)

    const int b  = blockIdx.x >> 4;
    const int pt = (blockIdx.x >> 2) & 3;
    const int sp = blockIdx.x & 3;
    const int t  = threadIdx.x;
    const int l  = t & 63;
    const int w  = t >> 6;               // wave 0..15

    // ---- stage this block's 1024-pt slice (1 pt/thread, raw coords) ----
    {
        const float* pcs = pc + ((size_t)b * NN + (size_t)sp * NPTS) * 3;
        const float x = pcs[3*t+0], y = pcs[3*t+1], z = pcs[3*t+2];
        const float wq = (x*x + y*y) + z*z;
        cloud[t] = make_float4(x, y, z, wq);
    }

    // ---- 16 basis points per thread, -2 prefolded: p = pt*1024 + 64q + l ----
    float bxm2[NQ], bym2[NQ], bzm2[NQ];
    {
        const int pb = (pt << 10) + l;
        #pragma unroll
        for (int q = 0; q < NQ; ++q) {
            const float* bp = basis + 3*(pb + 64*q);
            bxm2[q] = -2.f * bp[0];
            bym2[q] = -2.f * bp[1];
            bzm2[q] = -2.f * bp[2];
        }
    }

    __syncthreads();

    float gm[NQ];
    int   cb[NQ];
    #pragma unroll
    for (int q = 0; q < NQ; ++q) { gm[q] = __builtin_inff(); cb[q] = 0; }

    for (int c = 0; c < NCH; ++c) {
        const float4* chunk = cloud + (w << 6) + (c << 4);   // 16 pts
        float cm[NQ];
        #pragma unroll
        for (int s = 0; s < 8; ++s) {
            const float4 A0 = chunk[2*s];     // wave-uniform -> broadcast
            const float4 A1 = chunk[2*s+1];
            #pragma unroll
            for (int q = 0; q < NQ; ++q) {
                const float d0 = fmaf(A0.x, bxm2[q], fmaf(A0.y, bym2[q], fmaf(A0.z, bzm2[q], A0.w)));
                const float d1 = fmaf(A1.x, bxm2[q], fmaf(A1.y, bym2[q], fmaf(A1.z, bzm2[q], A1.w)));
                cm[q] = (s == 0) ? fminf(d0, d1) : min3f(cm[q], d0, d1);
            }
        }
        const int C = (sp << 6) + (w << 2) + c;   // global chunk id, ascending n
        #pragma unroll
        for (int q = 0; q < NQ; ++q)
            if (cm[q] < gm[q]) { gm[q] = cm[q]; cb[q] = C; }
    }

    #pragma unroll
    for (int q = 0; q < NQ; ++q)
        red[w][q][l] = make_float2(gm[q], __int_as_float(cb[q]));

    __syncthreads();

    // ---- merge 16 waves lexicographically, write per-split partial ----
    {
        const int q  = t >> 6;
        const int l2 = t & 63;
        float2 r0 = red[0][q][l2];
        float bm = r0.x;
        int   bC = __float_as_int(r0.y);
        #pragma unroll
        for (int w2 = 1; w2 < NW; ++w2) {
            const float2 r = red[w2][q][l2];
            const float v = r.x;
            const int   i = __float_as_int(r.y);
            if (v < bm || (v == bm && i < bC)) { bm = v; bC = i; }
        }
        const int p = (pt << 10) + t;
        val_ws[((size_t)sp << 16) + ((size_t)b << 12) + p] = bm;
        idx_ws[((size_t)sp << 16) + ((size_t)b << 12) + p] = bC;
    }
}

// ---------------- merge: combine splits, rescan winning chunk, emit ----------------
__global__ __launch_bounds__(256) void bps_merge(
    const float* __restrict__ pc,     // [B, N, 3]
    const float* __restrict__ basis,  // [P, 3]
    const float* __restrict__ val_ws,
    const int*   __restrict__ idx_ws,
    float* __restrict__ out)          // [B, P, 4]
{
#pragma clang fp contract(off)
    const int gid = blockIdx.x * 256 + threadIdx.x;   // 0..65535
    const int b   = gid >> 12;
    const int p   = gid & 4095;

    float bm = val_ws[((size_t)b << 12) + p];
    int   bC = idx_ws[((size_t)b << 12) + p];
    #pragma unroll
    for (int s = 1; s < NSPLIT; ++s) {
        const float v = val_ws[((size_t)s << 16) + ((size_t)b << 12) + p];
        const int   i = idx_ws[((size_t)s << 16) + ((size_t)b << 12) + p];
        if (v < bm || (v == bm && i < bC)) { bm = v; bC = i; }
    }

    const float bx = basis[3*p+0], by = basis[3*p+1], bz = basis[3*p+2];
    const float bxm2 = -2.f * bx, bym2 = -2.f * by, bzm2 = -2.f * bz;

    // rescan 16-pt chunk bC from pc with the IDENTICAL fma chain
    const float4* pp = (const float4*)(pc + (size_t)b * NN * 3) + 12 * bC;
    float4 F[12];
    #pragma unroll
    for (int j = 0; j < 12; ++j) F[j] = pp[j];
    const float* Ff = (const float*)F;

    int found = 0;
    float nx = 0.f, ny = 0.f, nz = 0.f;
    #pragma unroll
    for (int j = 0; j < 16; ++j) {           // ascending n -> first-index tie-break
        const float x = Ff[3*j+0];
        const float y = Ff[3*j+1];
        const float z = Ff[3*j+2];
        const float wq  = (x*x + y*y) + z*z;                 // == staging w
        const float key = fmaf(x, bxm2, fmaf(y, bym2, fmaf(z, bzm2, wq)));
        if (!found && key == bm) { found = 1; nx = x; ny = y; nz = z; }
    }

    const float dx = nx - bx, dy = ny - by, dz = nz - bz;
    const float dist = sqrtf((dx*dx + dy*dy) + dz*dz);
    ((float4*)out)[((size_t)b << 12) + p] = make_float4(dist, dx, dy, dz);
}

extern "C" void kernel_launch(void* const* d_in, const int* in_sizes, int n_in,
                              void* d_out, int out_size, void* d_ws, size_t ws_size,
                              hipStream_t stream) {
    const float* pc    = (const float*)d_in[0];  // [16, 4096, 3]
    const float* basis = (const float*)d_in[1];  // [4096, 3]
    float* out = (float*)d_out;                  // [16, 4096, 4]

    float* val_ws = (float*)d_ws;                        // 1 MB
    int*   idx_ws = (int*)d_ws + (NSPLIT << 16);         // 1 MB

    bps_main<<<dim3(NB * 4 * NSPLIT), dim3(THREADS), 0, stream>>>(pc, basis, val_ws, idx_ws);
    bps_merge<<<dim3(NB * NP / 256), dim3(256), 0, stream>>>(pc, basis, val_ws, idx_ws, out);
}